// Round 7
// baseline (156.058 us; speedup 1.0000x reference)
//
#include <hip/hip_runtime.h>
#include <math.h>

#ifndef M_PI
#define M_PI 3.14159265358979323846
#endif

// Problem constants (from the reference)
constexpr int    NSAMP  = 2048;
constexpr float  STEPf  = 2048.0f / 2047.0f;       // linspace(-1024,1024,2048) step
constexpr float  DXf    = 6.0e-6f;                 // 3e-6 / 0.5
constexpr float  EPSf   = 2.2204e-16f;
constexpr double Kd     = 2.0 * M_PI / 3.55e-7;    // ~1.7698956e7
constexpr double INV2PI = 1.0 / (2.0 * M_PI);

// ---------------------------------------------------------------------------
// Gather per-(batch,particle) parameters; precompute per-set constants (fp64).
// prm layout per (b,p), stride 16:
//   0:xm 1:ym
//   per set s in {hat,gt} at offset 2+6s:
//     +0: carg2    = carg^2            (y = x^2 = carg2*r2; predicate y<64)
//     +1: crev     = carg/2pi
//     +2: c8       = 8/carg            (z = min(c8*invr, 1))
//     +3: csql     = (rs/2)*sqrt(0.636619772/carg)  (amp_l = csql*invr^1.5*B)
//     +4: campcarg = (rs/2)*carg       (amp_s = campcarg * nt(y)/den(y),
//                                       since camp*invr*x == camp*carg)
//     +5: cph      = K/(2*zs*2pi)
// ---------------------------------------------------------------------------
__global__ void gather_params_kernel(const float* __restrict__ yh,
                                     const float* __restrict__ ygt,
                                     const int*   __restrict__ xs,
                                     const int*   __restrict__ ys,
                                     float* __restrict__ prm,
                                     double* __restrict__ acc) {
    int t = threadIdx.x;
    if (t == 0) *acc = 0.0;   // zero accumulator every launch (graph replay safe)
    if (t < 8) {
        const int M = 512;
        int b = t >> 2, p = t & 3;
        int ix = xs[b * 4 + p];
        int iy = ys[b * 4 + p];
        float rs_h = 50.0f  * yh [((b * 3 + 2) * M + iy) * M + ix];
        float zs_h = 200.0f * yh [((b * 3 + 1) * M + iy) * M + ix];
        float rs_g =          ygt[((b * 5 + 2) * M + iy) * M + ix];
        float zs_g =          ygt[((b * 5 + 1) * M + iy) * M + ix];
        double rph = (double)rs_h * 1e-6, zph = (double)zs_h * 1e-3;
        double rpg = (double)rs_g * 1e-6, zpg = (double)zs_g * 1e-3;

        float* o = prm + t * 16;
        o[0] = ((float)(ix * 4) - 1024.0f) * DXf;
        o[1] = ((float)(iy * 4) - 1024.0f) * DXf;

        double carg_h = Kd * rph / zph;
        o[2] = (float)(carg_h * carg_h);
        o[3] = (float)(carg_h * INV2PI);
        o[4] = (float)(8.0 / carg_h);
        o[5] = (float)(0.5 * rph * sqrt(0.636619772 / carg_h));
        o[6] = (float)(0.5 * rph * carg_h);
        o[7] = (float)(Kd / (2.0 * zph) * INV2PI);

        double carg_g = Kd * rpg / zpg;
        o[8]  = (float)(carg_g * carg_g);
        o[9]  = (float)(carg_g * INV2PI);
        o[10] = (float)(8.0 / carg_g);
        o[11] = (float)(0.5 * rpg * sqrt(0.636619772 / carg_g));
        o[12] = (float)(0.5 * rpg * carg_g);
        o[13] = (float)(Kd / (2.0 * zpg) * INV2PI);
        o[14] = 0.0f; o[15] = 0.0f;
    }
}

// One particle-set J1*trig contribution. The asymptotic (large-x) amplitude is
// always computed; the NR rational runs under a divergent if — waves with no
// lane inside the x<8 disc skip it via s_cbranch_execz (~93% of wave-calls).
__device__ __forceinline__ void accum_set(float carg2, float crev, float c8,
                                          float csql, float campcarg, float cph,
                                          float rho, float invr, float r2,
                                          float ivs /* invr^1.5, shared */,
                                          float& S, float& C) {
    float y = carg2 * r2;                 // x^2; predicate and poly variable
    // --- large branch (always): truncated asymptotic, z clamped ---
    float z    = fminf(c8 * invr, 1.0f);
    float y2   = z * z;
    float rev1 = fmaf(crev, rho, -0.375f);        // (x - 3pi/4)/2pi
    float f1   = __builtin_amdgcn_fractf(rev1);
    float s1   = __builtin_amdgcn_sinf(f1);
    float c1   = __builtin_amdgcn_cosf(f1);
    float p1   = fmaf(y2, 0.183105e-2f, 1.0f);
    float p2   = fmaf(y2, -0.2002690873e-3f, 0.04687499995f);
    float amp  = (csql * ivs) * fmaf(c1, p1, -(z * s1) * p2);
    // --- small branch (exec-masked): NR rational in y, amp overwrite ---
    if (y < 64.0f) {
        float nt  = fmaf(y, fmaf(y, fmaf(y, fmaf(y, fmaf(y,
                        -30.16036606f, 15704.48260f), -2972611.439f),
                        242396853.1f), -7895059235.0f), 72362614232.0f);
        float den = fmaf(y, fmaf(y, fmaf(y, fmaf(y, (y + 376.9991397f),
                        99447.43394f), 18583304.74f), 2300535178.0f), 144725228442.0f);
        amp = (campcarg * nt) * __builtin_amdgcn_rcpf(den);
    }
    // --- phase: rev = cph*r2, FMA residual restores low bits ---
    float hi  = cph * r2;
    float err = fmaf(cph, r2, -hi);
    float fr  = __builtin_amdgcn_fractf(hi) + err;
    float s2  = __builtin_amdgcn_sinf(fr);
    float c2  = __builtin_amdgcn_cosf(fr);
    S = fmaf(amp, s2, S);
    C = fmaf(amp, c2, C);
}

// 4096 blocks x 256 threads; each thread does 8 points (same j, rows i0+256k),
// block-uniform batch index.
__global__ __launch_bounds__(256, 4) void holo_mse_kernel(
        const float* __restrict__ prm, double* __restrict__ acc) {
    __shared__ float sp[128];
    __shared__ float wsum[4];
    if (threadIdx.x < 128) sp[threadIdx.x] = prm[threadIdx.x];
    __syncthreads();

    int blk = blockIdx.x;
    int b   = blk >> 11;                            // block-uniform batch
    int r   = ((blk & 2047) << 8) + threadIdx.x;    // [0, 524288)
    int i0  = r >> 11;                              // row base (0..255)
    int j   = r & (NSAMP - 1);

    float nj = fmaf((float)j, STEPf, -1024.0f) * DXf;
    float ni[8];
    #pragma unroll
    for (int k = 0; k < 8; ++k)
        ni[k] = fmaf((float)(i0 + 256 * k), STEPf, -1024.0f) * DXf;

    float Sh[8], Ch[8], Sg[8], Cg[8];
    #pragma unroll
    for (int k = 0; k < 8; ++k) { Sh[k] = Ch[k] = Sg[k] = Cg[k] = 0.0f; }

    #pragma unroll
    for (int p = 0; p < 4; ++p) {
        const float* q = &sp[(b * 4 + p) * 16];
        float xm = q[0], ym = q[1];
        float carg2_h = q[2], crev_h = q[3], c8_h = q[4],
              csql_h  = q[5], cpc_h  = q[6], cph_h = q[7];
        float carg2_g = q[8], crev_g = q[9], c8_g = q[10],
              csql_g  = q[11], cpc_g = q[12], cph_g = q[13];
        float dx  = (nj - xm) + EPSf;
        float dx2 = dx * dx;
        #pragma unroll
        for (int k = 0; k < 8; ++k) {
            float dy   = (ni[k] - ym) + EPSf;
            float r2   = fmaf(dy, dy, dx2);
            float invr = __builtin_amdgcn_rsqf(r2);
            float rho  = r2 * invr;
            float ivs  = invr * __builtin_amdgcn_sqrtf(invr);  // invr^1.5, shared
            accum_set(carg2_h, crev_h, c8_h, csql_h, cpc_h, cph_h,
                      rho, invr, r2, ivs, Sh[k], Ch[k]);
            accum_set(carg2_g, crev_g, c8_g, csql_g, cpc_g, cph_g,
                      rho, invr, r2, ivs, Sg[k], Cg[k]);
        }
    }

    float accd = 0.0f;
    #pragma unroll
    for (int k = 0; k < 8; ++k) {
        float reh = Sh[k] - 1.0f, reg = Sg[k] - 1.0f;
        float vh  = fmaf(reh, reh, Ch[k] * Ch[k]);
        float vg  = fmaf(reg, reg, Cg[k] * Cg[k]);
        float d   = vh - vg;
        accd = fmaf(d, d, accd);
    }

    #pragma unroll
    for (int off = 32; off > 0; off >>= 1) accd += __shfl_down(accd, off, 64);
    if ((threadIdx.x & 63) == 0) wsum[threadIdx.x >> 6] = accd;
    __syncthreads();
    if (threadIdx.x == 0) {
        float s = (wsum[0] + wsum[1]) + (wsum[2] + wsum[3]);
        atomicAdd(acc, (double)s);
    }
}

__global__ void finalize_kernel(const double* __restrict__ acc, float* __restrict__ out) {
    // mse * N^2 / 384^2 = sum / (B*N^2) * N^2/384^2 = sum / (2*384^2)
    out[0] = (float)(acc[0] / 294912.0);
}

extern "C" void kernel_launch(void* const* d_in, const int* in_sizes, int n_in,
                              void* d_out, int out_size, void* d_ws, size_t ws_size,
                              hipStream_t stream) {
    const float* yh  = (const float*)d_in[0];   // y_hat (2,3,512,512) f32
    const float* ygt = (const float*)d_in[1];   // y     (2,5,512,512) f32
    const int*   xs  = (const int*)d_in[2];     // (2,4) i32
    const int*   ys  = (const int*)d_in[3];     // (2,4) i32

    double* acc = (double*)d_ws;
    float*  prm = (float*)((char*)d_ws + 16);
    float*  out = (float*)d_out;

    gather_params_kernel<<<1, 128, 0, stream>>>(yh, ygt, xs, ys, prm, acc);
    holo_mse_kernel<<<4096, 256, 0, stream>>>(prm, acc);
    finalize_kernel<<<1, 1, 0, stream>>>(acc, out);
}